// Round 2
// baseline (1623.321 us; speedup 1.0000x reference)
//
#include <hip/hip_runtime.h>
#include <math.h>

// Shapes (fixed by the problem): b=4, c=512, l=4096, 32 groups.
// Inputs/outputs are float32; internal compute path is bf16 MFMA (comparison
// is done at bf16 precision with an 8-ulp floor).
#define BB 4
#define CC 512
#define LL 4096
#define NG 32
#define CPG 16
#define EPSV 1e-6f

typedef short s16x8 __attribute__((ext_vector_type(8)));
typedef __bf16 bf8v __attribute__((ext_vector_type(8)));
typedef float f32x4 __attribute__((ext_vector_type(4)));
typedef unsigned short u16;

static __device__ __forceinline__ float bf2f(u16 h) {
    unsigned int u = ((unsigned int)h) << 16;
    union { unsigned int u; float f; } c; c.u = u; return c.f;
}
static __device__ __forceinline__ u16 f2bf(float f) {
    union { float f; unsigned int u; } c; c.f = f;
    unsigned int lsb = (c.u >> 16) & 1u;
    c.u += 0x7fffu + lsb;           // round-to-nearest-even
    return (u16)(c.u >> 16);
}
static __device__ __forceinline__ bf8v ld_bf8(const u16* p) {
    return *reinterpret_cast<const bf8v*>(p);
}

// ---------------- weight convert: four 512x512 f32 -> bf16 ----------------
__global__ __launch_bounds__(256) void wconv_kernel(const float* __restrict__ w0,
                                                    const float* __restrict__ w1,
                                                    const float* __restrict__ w2,
                                                    const float* __restrict__ w3,
                                                    u16* __restrict__ wbf) {
    int i = blockIdx.x * 256 + threadIdx.x;      // 0..65535 float4 chunks
    int wsel = blockIdx.y;
    const float* src = (wsel == 0) ? w0 : (wsel == 1) ? w1 : (wsel == 2) ? w2 : w3;
    float4 v = reinterpret_cast<const float4*>(src)[i];
    ushort4 o;
    o.x = f2bf(v.x); o.y = f2bf(v.y); o.z = f2bf(v.z); o.w = f2bf(v.w);
    reinterpret_cast<ushort4*>(wbf + (size_t)wsel * CC * CC)[i] = o;
}

// ---------------- GroupNorm stats: one block per (group, batch) ----------------
__global__ __launch_bounds__(256) void gn_stats_kernel(const float* __restrict__ x,
                                                       float2* __restrict__ stats) {
    int g = blockIdx.x, b = blockIdx.y, t = threadIdx.x;
    const float4* xp = reinterpret_cast<const float4*>(x + ((size_t)b * CC + (size_t)g * CPG) * LL);
    float s = 0.f, ss = 0.f;
    // 16 channels * 4096 = 65536 f32 = 16384 float4; 64 per thread, coalesced.
    for (int it = 0; it < 64; ++it) {
        float4 v = xp[it * 256 + t];
        s += v.x + v.y + v.z + v.w;
        ss += v.x * v.x + v.y * v.y + v.z * v.z + v.w * v.w;
    }
    #pragma unroll
    for (int off = 32; off; off >>= 1) { s += __shfl_xor(s, off, 64); ss += __shfl_xor(ss, off, 64); }
    __shared__ float rs[4], rss[4];
    int wave = t >> 6, lane = t & 63;
    if (lane == 0) { rs[wave] = s; rss[wave] = ss; }
    __syncthreads();
    if (t == 0) {
        float S = rs[0] + rs[1] + rs[2] + rs[3];
        float SS = rss[0] + rss[1] + rss[2] + rss[3];
        float mean = S * (1.f / 65536.f);
        float var = SS * (1.f / 65536.f) - mean * mean;
        var = fmaxf(var, 0.f);
        stats[b * NG + g] = make_float2(mean, rsqrtf(var + EPSV));
    }
}

// -------- GroupNorm normalize + transpose: x[b][c][l] f32 -> hT[b][l][c] bf16 --------
__global__ __launch_bounds__(256) void gn_norm_t_kernel(const float* __restrict__ x,
                                                        const float2* __restrict__ stats,
                                                        const float* __restrict__ gsc,
                                                        const float* __restrict__ gbi,
                                                        u16* __restrict__ hT) {
    int lt = blockIdx.x, ct = blockIdx.y, b = blockIdx.z;
    __shared__ u16 tile[64][72];
    int t = threadIdx.x;
    int cl0 = t >> 4, c4 = (t & 15) * 4;
    #pragma unroll
    for (int p = 0; p < 4; ++p) {
        int cl = p * 16 + cl0;               // channel within tile
        int cg = ct * 64 + cl;               // global channel
        float2 st = stats[b * NG + (cg >> 4)];
        float sc = gsc[cg] * st.y;
        float bi = gbi[cg];
        float4 v = *reinterpret_cast<const float4*>(x + ((size_t)b * CC + cg) * LL + lt * 64 + c4);
        tile[cl][c4 + 0] = f2bf((v.x - st.x) * sc + bi);
        tile[cl][c4 + 1] = f2bf((v.y - st.x) * sc + bi);
        tile[cl][c4 + 2] = f2bf((v.z - st.x) * sc + bi);
        tile[cl][c4 + 3] = f2bf((v.w - st.x) * sc + bi);
    }
    __syncthreads();
    int r = t >> 3, c8 = (t & 7) * 8;
    #pragma unroll
    for (int p = 0; p < 2; ++p) {
        int ll = p * 32 + r;                 // l within tile
        s16x8 ov;
        #pragma unroll
        for (int j = 0; j < 8; ++j) ov[j] = (short)tile[c8 + j][ll];
        u16* hp = hT + ((size_t)b * LL + lt * 64 + ll) * CC + ct * 64 + c8;
        *reinterpret_cast<s16x8*>(hp) = ov;
    }
}

// ------------- plain bf16 transpose: src[b][4096][512] -> dst[b][512][4096] -------------
__global__ __launch_bounds__(256) void transpose_kernel(const u16* __restrict__ src,
                                                        u16* __restrict__ dst) {
    int rt = blockIdx.x, ct = blockIdx.y, b = blockIdx.z;
    __shared__ u16 tile[64][72];
    int t = threadIdx.x, r = t >> 3, c8 = (t & 7) * 8;
    #pragma unroll
    for (int p = 0; p < 2; ++p) {
        int rr = p * 32 + r;
        const u16* sp = src + ((size_t)b * LL + rt * 64 + rr) * CC + ct * 64 + c8;
        *reinterpret_cast<s16x8*>(&tile[rr][c8]) = *reinterpret_cast<const s16x8*>(sp);
    }
    __syncthreads();
    #pragma unroll
    for (int p = 0; p < 2; ++p) {
        int cc = p * 32 + r;
        s16x8 ov;
        #pragma unroll
        for (int j = 0; j < 8; ++j) ov[j] = (short)tile[c8 + j][cc];
        u16* dp = dst + ((size_t)b * CC + ct * 64 + cc) * LL + rt * 64 + c8;
        *reinterpret_cast<s16x8*>(dp) = ov;
    }
}

// --- final: out[b][co][l] = x[b][co][l] + pT[b][l][co]  (transpose + residual, f32 out) ---
__global__ __launch_bounds__(256) void final_kernel(const u16* __restrict__ pT,
                                                    const float* __restrict__ x,
                                                    float* __restrict__ out) {
    int lt = blockIdx.x, ct = blockIdx.y, b = blockIdx.z;
    __shared__ u16 tile[64][72];
    int t = threadIdx.x, r = t >> 3, c8 = (t & 7) * 8;
    #pragma unroll
    for (int p = 0; p < 2; ++p) {
        int rr = p * 32 + r;
        const u16* sp = pT + ((size_t)b * LL + lt * 64 + rr) * CC + ct * 64 + c8;
        *reinterpret_cast<s16x8*>(&tile[rr][c8]) = *reinterpret_cast<const s16x8*>(sp);
    }
    __syncthreads();
    #pragma unroll
    for (int p = 0; p < 2; ++p) {
        int cc = p * 32 + r;
        size_t off = ((size_t)b * CC + ct * 64 + cc) * LL + lt * 64 + c8;
        float4 x0 = *reinterpret_cast<const float4*>(x + off);
        float4 x1 = *reinterpret_cast<const float4*>(x + off + 4);
        float4 o0, o1;
        o0.x = x0.x + bf2f(tile[c8 + 0][cc]);
        o0.y = x0.y + bf2f(tile[c8 + 1][cc]);
        o0.z = x0.z + bf2f(tile[c8 + 2][cc]);
        o0.w = x0.w + bf2f(tile[c8 + 3][cc]);
        o1.x = x1.x + bf2f(tile[c8 + 4][cc]);
        o1.y = x1.y + bf2f(tile[c8 + 5][cc]);
        o1.z = x1.z + bf2f(tile[c8 + 6][cc]);
        o1.w = x1.w + bf2f(tile[c8 + 7][cc]);
        *reinterpret_cast<float4*>(out + off) = o0;
        *reinterpret_cast<float4*>(out + off + 4) = o1;
    }
}

// --------------- GEMM: Out[b][m][n] = sum_k A[b][m][k] * W[n][k] + bias[n] ---------------
// M=4096 (l), N=512 (co), K=512 (ci). 128x128 block tile, BK=32, 4 waves 2x2.
__global__ __launch_bounds__(256) void gemm_kernel(const u16* __restrict__ Ain,
                                                   const u16* __restrict__ W,
                                                   const float* __restrict__ bias,
                                                   u16* __restrict__ Out) {
    const int M = LL, K = CC, N = CC;
    int mt = blockIdx.x, nt = blockIdx.y, b = blockIdx.z;
    __shared__ u16 As[128 * 40];
    __shared__ u16 Bs[128 * 40];
    int t = threadIdx.x;
    int wave = t >> 6, lane = t & 63;
    int wm = (wave >> 1) * 64, wn = (wave & 1) * 64;
    int l15 = lane & 15, quad = lane >> 4;
    f32x4 acc[4][4] = {};
    const u16* Ab = Ain + ((size_t)b * M + mt * 128) * K;
    const u16* Wb = W + (size_t)nt * 128 * K;
    for (int k0 = 0; k0 < K; k0 += 32) {
        __syncthreads();
        #pragma unroll
        for (int ch = 0; ch < 2; ++ch) {
            int cid = ch * 256 + t;              // 512 chunks of 8 halfs
            int row = cid >> 2, ko = (cid & 3) * 8;
            *reinterpret_cast<s16x8*>(&As[row * 40 + ko]) =
                *reinterpret_cast<const s16x8*>(Ab + (size_t)row * K + k0 + ko);
            *reinterpret_cast<s16x8*>(&Bs[row * 40 + ko]) =
                *reinterpret_cast<const s16x8*>(Wb + (size_t)row * K + k0 + ko);
        }
        __syncthreads();
        bf8v af[4], bfr[4];
        #pragma unroll
        for (int i = 0; i < 4; ++i)
            af[i] = ld_bf8(&As[(wm + i * 16 + l15) * 40 + quad * 8]);
        #pragma unroll
        for (int j = 0; j < 4; ++j)
            bfr[j] = ld_bf8(&Bs[(wn + j * 16 + l15) * 40 + quad * 8]);
        #pragma unroll
        for (int i = 0; i < 4; ++i)
            #pragma unroll
            for (int j = 0; j < 4; ++j)
                acc[i][j] = __builtin_amdgcn_mfma_f32_16x16x32_bf16(af[i], bfr[j], acc[i][j], 0, 0, 0);
    }
    int m_base = mt * 128 + wm, n_base = nt * 128 + wn;
    u16* Ob = Out + ((size_t)b * M + m_base) * N + n_base;
    #pragma unroll
    for (int j = 0; j < 4; ++j) {
        float bv = bias[n_base + j * 16 + l15];
        #pragma unroll
        for (int i = 0; i < 4; ++i) {
            #pragma unroll
            for (int r = 0; r < 4; ++r) {
                int m = i * 16 + quad * 4 + r;
                Ob[(size_t)m * N + j * 16 + l15] = f2bf(acc[i][j][r] + bv);
            }
        }
    }
}

// ------------------------- fused attention (flash-style) -------------------------
// qT,kT: [b][l][c] bf16; v: [b][c][l] bf16; h2T out: [b][l][c] bf16.
__global__ __launch_bounds__(256) void attn_kernel(const u16* __restrict__ qT,
                                                   const u16* __restrict__ kT,
                                                   const u16* __restrict__ v,
                                                   u16* __restrict__ h2T) {
    const int D = CC;
    int b = blockIdx.y;
    int i0 = blockIdx.x * 32;
    int t = threadIdx.x;
    int wave = t >> 6, lane = t & 63;
    int l15 = lane & 15, quad = lane >> 4;
    int ih = wave >> 1, jh = wave & 1;
    int cb = jh * 256;                         // c-half for PV phase

    __shared__ float SL[32 * 68];
    __shared__ u16 PL[32 * 72];
    __shared__ float mL[32], lL[32], aL[32];

    if (t < 32) { mL[t] = -1e30f; lL[t] = 0.f; }

    f32x4 opv[16] = {};
    const u16* qb = qT + ((size_t)b * LL + i0 + ih * 16 + l15) * D + quad * 8;
    const u16* kb = kT + (size_t)b * LL * D;
    const u16* vb = v + (size_t)b * D * LL;
    const float scale = 0.044194173824159216f; // 512^-0.5
    __syncthreads();

    for (int j0 = 0; j0 < LL; j0 += 64) {
        // ---- S = Q K^T for rows [i0+ih*16, +16), cols [j0+jh*32, +32) ----
        f32x4 sacc0 = {}, sacc1 = {};
        const u16* kp0 = kb + ((size_t)(j0 + jh * 32 + l15)) * D + quad * 8;
        const u16* kp1 = kp0 + (size_t)16 * D;
        #pragma unroll
        for (int kc = 0; kc < 16; ++kc) {
            bf8v a = ld_bf8(qb + kc * 32);
            bf8v b0 = ld_bf8(kp0 + kc * 32);
            bf8v b1 = ld_bf8(kp1 + kc * 32);
            sacc0 = __builtin_amdgcn_mfma_f32_16x16x32_bf16(a, b0, sacc0, 0, 0, 0);
            sacc1 = __builtin_amdgcn_mfma_f32_16x16x32_bf16(a, b1, sacc1, 0, 0, 0);
        }
        #pragma unroll
        for (int r = 0; r < 4; ++r) {
            SL[(ih * 16 + quad * 4 + r) * 68 + jh * 32 + l15] = sacc0[r] * scale;
            SL[(ih * 16 + quad * 4 + r) * 68 + jh * 32 + 16 + l15] = sacc1[r] * scale;
        }
        __syncthreads();
        // ---- online softmax over this 64-col strip; 8 threads per row ----
        {
            int row = t >> 3, c8 = (t & 7) * 8;
            float4 s0 = *reinterpret_cast<const float4*>(&SL[row * 68 + c8]);
            float4 s1 = *reinterpret_cast<const float4*>(&SL[row * 68 + c8 + 4]);
            float sv[8] = { s0.x, s0.y, s0.z, s0.w, s1.x, s1.y, s1.z, s1.w };
            float mx = sv[0];
            #pragma unroll
            for (int j = 1; j < 8; ++j) mx = fmaxf(mx, sv[j]);
            #pragma unroll
            for (int off = 1; off < 8; off <<= 1) mx = fmaxf(mx, __shfl_xor(mx, off, 64));
            float mold = mL[row];
            float mnew = fmaxf(mold, mx);
            float alpha = __expf(mold - mnew);
            float s = 0.f;
            #pragma unroll
            for (int j = 0; j < 8; ++j) { float p = __expf(sv[j] - mnew); sv[j] = p; s += p; }
            #pragma unroll
            for (int off = 1; off < 8; off <<= 1) s += __shfl_xor(s, off, 64);
            ushort4 p0, p1;
            p0.x = f2bf(sv[0]); p0.y = f2bf(sv[1]); p0.z = f2bf(sv[2]); p0.w = f2bf(sv[3]);
            p1.x = f2bf(sv[4]); p1.y = f2bf(sv[5]); p1.z = f2bf(sv[6]); p1.w = f2bf(sv[7]);
            *reinterpret_cast<ushort4*>(&PL[row * 72 + c8]) = p0;
            *reinterpret_cast<ushort4*>(&PL[row * 72 + c8 + 4]) = p1;
            if ((t & 7) == 0) {
                lL[row] = lL[row] * alpha + s;
                mL[row] = mnew;
                aL[row] = alpha;
            }
        }
        __syncthreads();
        // ---- PV: rescale acc by alpha, then acc += P * V ----
        float al[4];
        #pragma unroll
        for (int r = 0; r < 4; ++r) al[r] = aL[ih * 16 + quad * 4 + r];
        #pragma unroll
        for (int nt2 = 0; nt2 < 16; ++nt2)
            #pragma unroll
            for (int r = 0; r < 4; ++r) opv[nt2][r] *= al[r];
        #pragma unroll
        for (int kk = 0; kk < 2; ++kk) {
            bf8v pa = ld_bf8(&PL[(ih * 16 + l15) * 72 + kk * 32 + quad * 8]);
            #pragma unroll
            for (int nt2 = 0; nt2 < 16; ++nt2) {
                const u16* vp = vb + (size_t)(cb + nt2 * 16 + l15) * LL + j0 + kk * 32 + quad * 8;
                bf8v bv = ld_bf8(vp);
                opv[nt2] = __builtin_amdgcn_mfma_f32_16x16x32_bf16(pa, bv, opv[nt2], 0, 0, 0);
            }
        }
        __syncthreads();
    }
    float il[4];
    #pragma unroll
    for (int r = 0; r < 4; ++r) il[r] = 1.f / lL[ih * 16 + quad * 4 + r];
    #pragma unroll
    for (int nt2 = 0; nt2 < 16; ++nt2) {
        #pragma unroll
        for (int r = 0; r < 4; ++r) {
            int irow = ih * 16 + quad * 4 + r;
            h2T[((size_t)b * LL + i0 + irow) * D + cb + nt2 * 16 + l15] = f2bf(opv[nt2][r] * il[r]);
        }
    }
}

extern "C" void kernel_launch(void* const* d_in, const int* in_sizes, int n_in,
                              void* d_out, int out_size, void* d_ws, size_t ws_size,
                              hipStream_t stream) {
    const float* x   = (const float*)d_in[0];
    const float* gsc = (const float*)d_in[1];
    const float* gbi = (const float*)d_in[2];
    const float* wq  = (const float*)d_in[3];
    const float* bq  = (const float*)d_in[4];
    const float* wk  = (const float*)d_in[5];
    const float* bk  = (const float*)d_in[6];
    const float* wv  = (const float*)d_in[7];
    const float* bv  = (const float*)d_in[8];
    const float* wp  = (const float*)d_in[9];
    const float* bp  = (const float*)d_in[10];
    float* out = (float*)d_out;

    char* ws = (char*)d_ws;
    const size_t SZ = (size_t)BB * LL * CC * 2;    // 16 MiB per [b][l][c] bf16 buffer
    u16* buf0 = (u16*)(ws);                        // hT, then vv
    u16* buf1 = (u16*)(ws + SZ);                   // qT, then pT
    u16* buf2 = (u16*)(ws + 2 * SZ);               // kT
    u16* buf3 = (u16*)(ws + 3 * SZ);               // vT, then h2T
    u16* wbf  = (u16*)(ws + 4 * SZ);               // 4x 512x512 bf16 weights (2 MiB)
    float2* stats = (float2*)(ws + 4 * SZ + (size_t)4 * CC * CC * 2);

    wconv_kernel<<<dim3(256, 4), 256, 0, stream>>>(wq, wk, wv, wp, wbf);
    gn_stats_kernel<<<dim3(NG, BB), 256, 0, stream>>>(x, stats);
    gn_norm_t_kernel<<<dim3(64, 8, BB), 256, 0, stream>>>(x, stats, gsc, gbi, buf0);
    gemm_kernel<<<dim3(32, 4, BB), 256, 0, stream>>>(buf0, wbf + 0 * CC * CC, bq, buf1);
    gemm_kernel<<<dim3(32, 4, BB), 256, 0, stream>>>(buf0, wbf + 1 * CC * CC, bk, buf2);
    gemm_kernel<<<dim3(32, 4, BB), 256, 0, stream>>>(buf0, wbf + 2 * CC * CC, bv, buf3);
    transpose_kernel<<<dim3(64, 8, BB), 256, 0, stream>>>(buf3, buf0);   // vT -> vv
    attn_kernel<<<dim3(LL / 32, BB), 256, 0, stream>>>(buf1, buf2, buf0, buf3); // -> h2T
    gemm_kernel<<<dim3(32, 4, BB), 256, 0, stream>>>(buf3, wbf + 3 * CC * CC, bp, buf1); // -> pT
    final_kernel<<<dim3(64, 8, BB), 256, 0, stream>>>(buf1, x, out);
}

// Round 3
// 467.852 us; speedup vs baseline: 3.4697x; 3.4697x over previous
//
#include <hip/hip_runtime.h>
#include <math.h>

// Shapes (fixed by the problem): b=4, c=512, l=4096, 32 groups.
// Inputs/outputs are float32; internal compute path is bf16 MFMA.
#define BB 4
#define CC 512
#define LL 4096
#define NG 32
#define CPG 16
#define EPSV 1e-6f

typedef short s16x8 __attribute__((ext_vector_type(8)));
typedef __bf16 bf8v __attribute__((ext_vector_type(8)));
typedef float f32x4 __attribute__((ext_vector_type(4)));
typedef unsigned short u16;

typedef const __attribute__((address_space(1))) void g1_void;
typedef __attribute__((address_space(3))) void l3_void;

static __device__ __forceinline__ float bf2f(u16 h) {
    unsigned int u = ((unsigned int)h) << 16;
    union { unsigned int u; float f; } c; c.u = u; return c.f;
}
static __device__ __forceinline__ u16 f2bf(float f) {
    union { float f; unsigned int u; } c; c.f = f;
    unsigned int lsb = (c.u >> 16) & 1u;
    c.u += 0x7fffu + lsb;           // round-to-nearest-even
    return (u16)(c.u >> 16);
}
static __device__ __forceinline__ bf8v ld_bf8(const u16* p) {
    return *reinterpret_cast<const bf8v*>(p);
}
// async global->LDS, 16B per lane; lds dest = wave-uniform base + lane*16
static __device__ __forceinline__ void gload16(const u16* g, u16* l) {
    __builtin_amdgcn_global_load_lds((g1_void*)g, (l3_void*)l, 16, 0, 0);
}

// ---------------- weight convert: four 512x512 f32 -> bf16 ----------------
__global__ __launch_bounds__(256) void wconv_kernel(const float* __restrict__ w0,
                                                    const float* __restrict__ w1,
                                                    const float* __restrict__ w2,
                                                    const float* __restrict__ w3,
                                                    u16* __restrict__ wbf) {
    int i = blockIdx.x * 256 + threadIdx.x;      // 0..65535 float4 chunks
    int wsel = blockIdx.y;
    const float* src = (wsel == 0) ? w0 : (wsel == 1) ? w1 : (wsel == 2) ? w2 : w3;
    float4 v = reinterpret_cast<const float4*>(src)[i];
    ushort4 o;
    o.x = f2bf(v.x); o.y = f2bf(v.y); o.z = f2bf(v.z); o.w = f2bf(v.w);
    reinterpret_cast<ushort4*>(wbf + (size_t)wsel * CC * CC)[i] = o;
}

// ---------------- GroupNorm stats: one block per (group, batch) ----------------
__global__ __launch_bounds__(256) void gn_stats_kernel(const float* __restrict__ x,
                                                       float2* __restrict__ stats) {
    int g = blockIdx.x, b = blockIdx.y, t = threadIdx.x;
    const float4* xp = reinterpret_cast<const float4*>(x + ((size_t)b * CC + (size_t)g * CPG) * LL);
    float s = 0.f, ss = 0.f;
    for (int it = 0; it < 64; ++it) {
        float4 v = xp[it * 256 + t];
        s += v.x + v.y + v.z + v.w;
        ss += v.x * v.x + v.y * v.y + v.z * v.z + v.w * v.w;
    }
    #pragma unroll
    for (int off = 32; off; off >>= 1) { s += __shfl_xor(s, off, 64); ss += __shfl_xor(ss, off, 64); }
    __shared__ float rs[4], rss[4];
    int wave = t >> 6, lane = t & 63;
    if (lane == 0) { rs[wave] = s; rss[wave] = ss; }
    __syncthreads();
    if (t == 0) {
        float S = rs[0] + rs[1] + rs[2] + rs[3];
        float SS = rss[0] + rss[1] + rss[2] + rss[3];
        float mean = S * (1.f / 65536.f);
        float var = SS * (1.f / 65536.f) - mean * mean;
        var = fmaxf(var, 0.f);
        stats[b * NG + g] = make_float2(mean, rsqrtf(var + EPSV));
    }
}

// -------- GroupNorm normalize + transpose: x[b][c][l] f32 -> hT[b][l][c] bf16 --------
__global__ __launch_bounds__(256) void gn_norm_t_kernel(const float* __restrict__ x,
                                                        const float2* __restrict__ stats,
                                                        const float* __restrict__ gsc,
                                                        const float* __restrict__ gbi,
                                                        u16* __restrict__ hT) {
    int lt = blockIdx.x, ct = blockIdx.y, b = blockIdx.z;
    __shared__ u16 tile[64][72];
    int t = threadIdx.x;
    int cl0 = t >> 4, c4 = (t & 15) * 4;
    #pragma unroll
    for (int p = 0; p < 4; ++p) {
        int cl = p * 16 + cl0;
        int cg = ct * 64 + cl;
        float2 st = stats[b * NG + (cg >> 4)];
        float sc = gsc[cg] * st.y;
        float bi = gbi[cg];
        float4 v = *reinterpret_cast<const float4*>(x + ((size_t)b * CC + cg) * LL + lt * 64 + c4);
        tile[cl][c4 + 0] = f2bf((v.x - st.x) * sc + bi);
        tile[cl][c4 + 1] = f2bf((v.y - st.x) * sc + bi);
        tile[cl][c4 + 2] = f2bf((v.z - st.x) * sc + bi);
        tile[cl][c4 + 3] = f2bf((v.w - st.x) * sc + bi);
    }
    __syncthreads();
    int r = t >> 3, c8 = (t & 7) * 8;
    #pragma unroll
    for (int p = 0; p < 2; ++p) {
        int ll = p * 32 + r;
        s16x8 ov;
        #pragma unroll
        for (int j = 0; j < 8; ++j) ov[j] = (short)tile[c8 + j][ll];
        u16* hp = hT + ((size_t)b * LL + lt * 64 + ll) * CC + ct * 64 + c8;
        *reinterpret_cast<s16x8*>(hp) = ov;
    }
}

// ------------- plain bf16 transpose: src[b][4096][512] -> dst[b][512][4096] -------------
__global__ __launch_bounds__(256) void transpose_kernel(const u16* __restrict__ src,
                                                        u16* __restrict__ dst) {
    int rt = blockIdx.x, ct = blockIdx.y, b = blockIdx.z;
    __shared__ u16 tile[64][72];
    int t = threadIdx.x, r = t >> 3, c8 = (t & 7) * 8;
    #pragma unroll
    for (int p = 0; p < 2; ++p) {
        int rr = p * 32 + r;
        const u16* sp = src + ((size_t)b * LL + rt * 64 + rr) * CC + ct * 64 + c8;
        *reinterpret_cast<s16x8*>(&tile[rr][c8]) = *reinterpret_cast<const s16x8*>(sp);
    }
    __syncthreads();
    #pragma unroll
    for (int p = 0; p < 2; ++p) {
        int cc = p * 32 + r;
        s16x8 ov;
        #pragma unroll
        for (int j = 0; j < 8; ++j) ov[j] = (short)tile[c8 + j][cc];
        u16* dp = dst + ((size_t)b * CC + ct * 64 + cc) * LL + rt * 64 + c8;
        *reinterpret_cast<s16x8*>(dp) = ov;
    }
}

// --- final: out[b][co][l] = x[b][co][l] + pT[b][l][co]  (transpose + residual, f32 out) ---
__global__ __launch_bounds__(256) void final_kernel(const u16* __restrict__ pT,
                                                    const float* __restrict__ x,
                                                    float* __restrict__ out) {
    int lt = blockIdx.x, ct = blockIdx.y, b = blockIdx.z;
    __shared__ u16 tile[64][72];
    int t = threadIdx.x, r = t >> 3, c8 = (t & 7) * 8;
    #pragma unroll
    for (int p = 0; p < 2; ++p) {
        int rr = p * 32 + r;
        const u16* sp = pT + ((size_t)b * LL + lt * 64 + rr) * CC + ct * 64 + c8;
        *reinterpret_cast<s16x8*>(&tile[rr][c8]) = *reinterpret_cast<const s16x8*>(sp);
    }
    __syncthreads();
    #pragma unroll
    for (int p = 0; p < 2; ++p) {
        int cc = p * 32 + r;
        size_t off = ((size_t)b * CC + ct * 64 + cc) * LL + lt * 64 + c8;
        float4 x0 = *reinterpret_cast<const float4*>(x + off);
        float4 x1 = *reinterpret_cast<const float4*>(x + off + 4);
        float4 o0, o1;
        o0.x = x0.x + bf2f(tile[c8 + 0][cc]);
        o0.y = x0.y + bf2f(tile[c8 + 1][cc]);
        o0.z = x0.z + bf2f(tile[c8 + 2][cc]);
        o0.w = x0.w + bf2f(tile[c8 + 3][cc]);
        o1.x = x1.x + bf2f(tile[c8 + 4][cc]);
        o1.y = x1.y + bf2f(tile[c8 + 5][cc]);
        o1.z = x1.z + bf2f(tile[c8 + 6][cc]);
        o1.w = x1.w + bf2f(tile[c8 + 7][cc]);
        *reinterpret_cast<float4*>(out + off) = o0;
        *reinterpret_cast<float4*>(out + off + 4) = o1;
    }
}

// ---------------- generic GEMM (m97 recipe): Out = A * B^T * scale + bias ----------------
// A: [batch via asb][M][K] bf16 (k-contiguous), B: [batch via bsb][N][K] bf16,
// Out: [batch via osb][M][N] bf16. 128x128 tile, BK=32, global_load_lds width 16,
// unpadded LDS (2-way bank alias is free), 4 waves 2x2, 16 MFMA/k-step/wave.
__global__ __launch_bounds__(256) void gemm_kernel(const u16* __restrict__ A, size_t asb,
                                                   const u16* __restrict__ B, size_t bsb,
                                                   const float* __restrict__ bias, float scale,
                                                   u16* __restrict__ Out, size_t osb,
                                                   int N, int K) {
    __shared__ u16 As[128 * 32];
    __shared__ u16 Bs[128 * 32];
    int mt = blockIdx.x, nt = blockIdx.y, b = blockIdx.z;
    int t = threadIdx.x;
    int wave = t >> 6, lane = t & 63;
    int wm = (wave >> 1) * 64, wn = (wave & 1) * 64;
    int l15 = lane & 15, quad = lane >> 4;
    f32x4 acc[4][4] = {};
    const u16* Ab = A + (size_t)b * asb + (size_t)mt * 128 * K;
    const u16* Bb = B + (size_t)b * bsb + (size_t)nt * 128 * K;
    // staging: 512 16B-chunks per buffer; chunk c -> row c>>2, k-offset (c&3)*8.
    int c0 = wave * 64 + lane, c1 = 256 + wave * 64 + lane;
    int r0 = c0 >> 2, k80 = (c0 & 3) * 8;
    int r1 = c1 >> 2, k81 = (c1 & 3) * 8;
    u16* As0 = As + wave * 512;        u16* As1 = As + 2048 + wave * 512;
    u16* Bs0 = Bs + wave * 512;        u16* Bs1 = Bs + 2048 + wave * 512;
    const u16* Ap0 = Ab + (size_t)r0 * K + k80;
    const u16* Ap1 = Ab + (size_t)r1 * K + k81;
    const u16* Bp0 = Bb + (size_t)r0 * K + k80;
    const u16* Bp1 = Bb + (size_t)r1 * K + k81;
    for (int k0 = 0; k0 < K; k0 += 32) {
        __syncthreads();
        gload16(Ap0 + k0, As0);
        gload16(Ap1 + k0, As1);
        gload16(Bp0 + k0, Bs0);
        gload16(Bp1 + k0, Bs1);
        __syncthreads();
        bf8v af[4], bfr[4];
        #pragma unroll
        for (int i = 0; i < 4; ++i)
            af[i] = ld_bf8(&As[(wm + i * 16 + l15) * 32 + quad * 8]);
        #pragma unroll
        for (int j = 0; j < 4; ++j)
            bfr[j] = ld_bf8(&Bs[(wn + j * 16 + l15) * 32 + quad * 8]);
        #pragma unroll
        for (int i = 0; i < 4; ++i)
            #pragma unroll
            for (int j = 0; j < 4; ++j)
                acc[i][j] = __builtin_amdgcn_mfma_f32_16x16x32_bf16(af[i], bfr[j], acc[i][j], 0, 0, 0);
    }
    int m_base = mt * 128 + wm, n_base = nt * 128 + wn;
    u16* Ob = Out + (size_t)b * osb + (size_t)m_base * N + n_base;
    #pragma unroll
    for (int j = 0; j < 4; ++j) {
        float bv = bias ? bias[n_base + j * 16 + l15] : 0.f;
        #pragma unroll
        for (int i = 0; i < 4; ++i) {
            #pragma unroll
            for (int r = 0; r < 4; ++r) {
                int m = i * 16 + quad * 4 + r;
                Ob[(size_t)m * N + j * 16 + l15] = f2bf(acc[i][j][r] * scale + bv);
            }
        }
    }
}

// --------------- exact row softmax over S[b][i][0..4096), in place, bf16 ---------------
__global__ __launch_bounds__(256) void softmax_kernel(u16* __restrict__ S) {
    size_t row = (size_t)blockIdx.y * LL + blockIdx.x;
    u16* p = S + row * LL;
    int t = threadIdx.x;
    int wave = t >> 6, lane = t & 63;
    s16x8 v0 = reinterpret_cast<const s16x8*>(p)[t];
    s16x8 v1 = reinterpret_cast<const s16x8*>(p)[t + 256];
    float f[16];
    #pragma unroll
    for (int j = 0; j < 8; ++j) { f[j] = bf2f((u16)v0[j]); f[8 + j] = bf2f((u16)v1[j]); }
    float mx = f[0];
    #pragma unroll
    for (int j = 1; j < 16; ++j) mx = fmaxf(mx, f[j]);
    #pragma unroll
    for (int off = 32; off; off >>= 1) mx = fmaxf(mx, __shfl_xor(mx, off, 64));
    __shared__ float red[4];
    if (lane == 0) red[wave] = mx;
    __syncthreads();
    mx = fmaxf(fmaxf(red[0], red[1]), fmaxf(red[2], red[3]));
    float s = 0.f;
    #pragma unroll
    for (int j = 0; j < 16; ++j) { f[j] = __expf(f[j] - mx); s += f[j]; }
    #pragma unroll
    for (int off = 32; off; off >>= 1) s += __shfl_xor(s, off, 64);
    __syncthreads();
    if (lane == 0) red[wave] = s;
    __syncthreads();
    s = red[0] + red[1] + red[2] + red[3];
    float inv = 1.f / s;
    s16x8 o0, o1;
    #pragma unroll
    for (int j = 0; j < 8; ++j) { o0[j] = (short)f2bf(f[j] * inv); o1[j] = (short)f2bf(f[8 + j] * inv); }
    reinterpret_cast<s16x8*>(p)[t] = o0;
    reinterpret_cast<s16x8*>(p)[t + 256] = o1;
}

// ------------------------- flash attention (FALLBACK path only) -------------------------
__global__ __launch_bounds__(256) void attn_kernel(const u16* __restrict__ qT,
                                                   const u16* __restrict__ kT,
                                                   const u16* __restrict__ v,
                                                   u16* __restrict__ h2T) {
    const int D = CC;
    int b = blockIdx.y;
    int i0 = blockIdx.x * 32;
    int t = threadIdx.x;
    int wave = t >> 6, lane = t & 63;
    int l15 = lane & 15, quad = lane >> 4;
    int ih = wave >> 1, jh = wave & 1;
    int cb = jh * 256;

    __shared__ float SL[32 * 68];
    __shared__ u16 PL[32 * 72];
    __shared__ float mL[32], lL[32], aL[32];

    if (t < 32) { mL[t] = -1e30f; lL[t] = 0.f; }

    f32x4 opv[16] = {};
    const u16* qb = qT + ((size_t)b * LL + i0 + ih * 16 + l15) * D + quad * 8;
    const u16* kb = kT + (size_t)b * LL * D;
    const u16* vb = v + (size_t)b * D * LL;
    const float scale = 0.044194173824159216f;
    __syncthreads();

    for (int j0 = 0; j0 < LL; j0 += 64) {
        f32x4 sacc0 = {}, sacc1 = {};
        const u16* kp0 = kb + ((size_t)(j0 + jh * 32 + l15)) * D + quad * 8;
        const u16* kp1 = kp0 + (size_t)16 * D;
        #pragma unroll
        for (int kc = 0; kc < 16; ++kc) {
            bf8v a = ld_bf8(qb + kc * 32);
            bf8v b0 = ld_bf8(kp0 + kc * 32);
            bf8v b1 = ld_bf8(kp1 + kc * 32);
            sacc0 = __builtin_amdgcn_mfma_f32_16x16x32_bf16(a, b0, sacc0, 0, 0, 0);
            sacc1 = __builtin_amdgcn_mfma_f32_16x16x32_bf16(a, b1, sacc1, 0, 0, 0);
        }
        #pragma unroll
        for (int r = 0; r < 4; ++r) {
            SL[(ih * 16 + quad * 4 + r) * 68 + jh * 32 + l15] = sacc0[r] * scale;
            SL[(ih * 16 + quad * 4 + r) * 68 + jh * 32 + 16 + l15] = sacc1[r] * scale;
        }
        __syncthreads();
        {
            int row = t >> 3, c8 = (t & 7) * 8;
            float4 s0 = *reinterpret_cast<const float4*>(&SL[row * 68 + c8]);
            float4 s1 = *reinterpret_cast<const float4*>(&SL[row * 68 + c8 + 4]);
            float sv[8] = { s0.x, s0.y, s0.z, s0.w, s1.x, s1.y, s1.z, s1.w };
            float mx = sv[0];
            #pragma unroll
            for (int j = 1; j < 8; ++j) mx = fmaxf(mx, sv[j]);
            #pragma unroll
            for (int off = 1; off < 8; off <<= 1) mx = fmaxf(mx, __shfl_xor(mx, off, 64));
            float mold = mL[row];
            float mnew = fmaxf(mold, mx);
            float alpha = __expf(mold - mnew);
            float s = 0.f;
            #pragma unroll
            for (int j = 0; j < 8; ++j) { float pp = __expf(sv[j] - mnew); sv[j] = pp; s += pp; }
            #pragma unroll
            for (int off = 1; off < 8; off <<= 1) s += __shfl_xor(s, off, 64);
            ushort4 p0, p1;
            p0.x = f2bf(sv[0]); p0.y = f2bf(sv[1]); p0.z = f2bf(sv[2]); p0.w = f2bf(sv[3]);
            p1.x = f2bf(sv[4]); p1.y = f2bf(sv[5]); p1.z = f2bf(sv[6]); p1.w = f2bf(sv[7]);
            *reinterpret_cast<ushort4*>(&PL[row * 72 + c8]) = p0;
            *reinterpret_cast<ushort4*>(&PL[row * 72 + c8 + 4]) = p1;
            if ((t & 7) == 0) {
                lL[row] = lL[row] * alpha + s;
                mL[row] = mnew;
                aL[row] = alpha;
            }
        }
        __syncthreads();
        float al[4];
        #pragma unroll
        for (int r = 0; r < 4; ++r) al[r] = aL[ih * 16 + quad * 4 + r];
        #pragma unroll
        for (int nt2 = 0; nt2 < 16; ++nt2)
            #pragma unroll
            for (int r = 0; r < 4; ++r) opv[nt2][r] *= al[r];
        #pragma unroll
        for (int kk = 0; kk < 2; ++kk) {
            bf8v pa = ld_bf8(&PL[(ih * 16 + l15) * 72 + kk * 32 + quad * 8]);
            #pragma unroll
            for (int nt2 = 0; nt2 < 16; ++nt2) {
                const u16* vp = vb + (size_t)(cb + nt2 * 16 + l15) * LL + j0 + kk * 32 + quad * 8;
                bf8v bv = ld_bf8(vp);
                opv[nt2] = __builtin_amdgcn_mfma_f32_16x16x32_bf16(pa, bv, opv[nt2], 0, 0, 0);
            }
        }
        __syncthreads();
    }
    float il[4];
    #pragma unroll
    for (int r = 0; r < 4; ++r) il[r] = 1.f / lL[ih * 16 + quad * 4 + r];
    #pragma unroll
    for (int nt2 = 0; nt2 < 16; ++nt2) {
        #pragma unroll
        for (int r = 0; r < 4; ++r) {
            int irow = ih * 16 + quad * 4 + r;
            h2T[((size_t)b * LL + i0 + irow) * D + cb + nt2 * 16 + l15] = f2bf(opv[nt2][r] * il[r]);
        }
    }
}

extern "C" void kernel_launch(void* const* d_in, const int* in_sizes, int n_in,
                              void* d_out, int out_size, void* d_ws, size_t ws_size,
                              hipStream_t stream) {
    const float* x   = (const float*)d_in[0];
    const float* gsc = (const float*)d_in[1];
    const float* gbi = (const float*)d_in[2];
    const float* wq  = (const float*)d_in[3];
    const float* bq  = (const float*)d_in[4];
    const float* wk  = (const float*)d_in[5];
    const float* bk  = (const float*)d_in[6];
    const float* wv  = (const float*)d_in[7];
    const float* bv  = (const float*)d_in[8];
    const float* wp  = (const float*)d_in[9];
    const float* bp  = (const float*)d_in[10];
    float* out = (float*)d_out;

    char* ws = (char*)d_ws;
    const size_t SZ   = (size_t)BB * LL * CC * 2;     // 16 MiB per [b][l][c] bf16 buffer
    const size_t WQSZ = (size_t)4 * CC * CC * 2;      // 2 MiB bf16 weights
    const size_t SSZ  = (size_t)BB * LL * LL * 2;     // 128 MiB bf16 scores (all batches)
    u16* bufA = (u16*)(ws);                  // hT -> vv
    u16* bufB = (u16*)(ws + SZ);             // qT -> pT
    u16* bufC = (u16*)(ws + 2 * SZ);         // kT
    u16* bufD = (u16*)(ws + 3 * SZ);         // vT -> h2T
    u16* wbf  = (u16*)(ws + 4 * SZ);
    float2* stats = (float2*)(ws + 4 * SZ + WQSZ);
    u16* Sbuf = (u16*)(ws + 4 * SZ + WQSZ + 4096);
    const size_t NEEDED = 4 * SZ + WQSZ + 4096 + SSZ;
    const float scale = 0.044194173824159216f;        // 512^-0.5
    const size_t BLC = (size_t)LL * CC;

    wconv_kernel<<<dim3(256, 4), 256, 0, stream>>>(wq, wk, wv, wp, wbf);
    gn_stats_kernel<<<dim3(NG, BB), 256, 0, stream>>>(x, stats);
    gn_norm_t_kernel<<<dim3(64, 8, BB), 256, 0, stream>>>(x, stats, gsc, gbi, bufA);
    gemm_kernel<<<dim3(32, 4, BB), 256, 0, stream>>>(bufA, BLC, wbf + 0 * CC * CC, 0, bq, 1.f, bufB, BLC, CC, CC);
    gemm_kernel<<<dim3(32, 4, BB), 256, 0, stream>>>(bufA, BLC, wbf + 1 * CC * CC, 0, bk, 1.f, bufC, BLC, CC, CC);
    gemm_kernel<<<dim3(32, 4, BB), 256, 0, stream>>>(bufA, BLC, wbf + 2 * CC * CC, 0, bv, 1.f, bufD, BLC, CC, CC);
    transpose_kernel<<<dim3(64, 8, BB), 256, 0, stream>>>(bufD, bufA);   // vT -> vv

    if (ws_size >= NEEDED) {
        // Two-pass attention: S = QK^T*scale (GEMM) -> exact softmax -> O = P V (GEMM)
        gemm_kernel<<<dim3(32, 32, BB), 256, 0, stream>>>(bufB, BLC, bufC, BLC, nullptr, scale,
                                                          Sbuf, (size_t)LL * LL, LL, CC);
        softmax_kernel<<<dim3(LL, BB), 256, 0, stream>>>(Sbuf);
        gemm_kernel<<<dim3(32, 4, BB), 256, 0, stream>>>(Sbuf, (size_t)LL * LL, bufA, (size_t)CC * LL,
                                                         nullptr, 1.f, bufD, BLC, CC, LL);
    } else {
        // Fallback: flash attention (round-2 path)
        attn_kernel<<<dim3(LL / 32, BB), 256, 0, stream>>>(bufB, bufC, bufA, bufD);
    }
    gemm_kernel<<<dim3(32, 4, BB), 256, 0, stream>>>(bufD, BLC, wbf + 3 * CC * CC, 0, bp, 1.f, bufB, BLC, CC, CC);
    final_kernel<<<dim3(64, 8, BB), 256, 0, stream>>>(bufB, x, out);
}

// Round 4
// 442.699 us; speedup vs baseline: 3.6669x; 1.0568x over previous
//
#include <hip/hip_runtime.h>
#include <math.h>

// Shapes (fixed by the problem): b=4, c=512, l=4096, 32 groups.
// Inputs/outputs are float32; internal compute path is bf16 MFMA.
#define BB 4
#define CC 512
#define LL 4096
#define NG 32
#define CPG 16
#define EPSV 1e-6f

typedef short s16x8 __attribute__((ext_vector_type(8)));
typedef __bf16 bf8v __attribute__((ext_vector_type(8)));
typedef float f32x4 __attribute__((ext_vector_type(4)));
typedef unsigned short u16;

typedef const __attribute__((address_space(1))) void g1_void;
typedef __attribute__((address_space(3))) void l3_void;

static __device__ __forceinline__ float bf2f(u16 h) {
    unsigned int u = ((unsigned int)h) << 16;
    union { unsigned int u; float f; } c; c.u = u; return c.f;
}
static __device__ __forceinline__ u16 f2bf(float f) {
    union { float f; unsigned int u; } c; c.f = f;
    unsigned int lsb = (c.u >> 16) & 1u;
    c.u += 0x7fffu + lsb;           // round-to-nearest-even
    return (u16)(c.u >> 16);
}
static __device__ __forceinline__ bf8v ld_bf8(const u16* p) {
    return *reinterpret_cast<const bf8v*>(p);
}
// async global->LDS; HW writes lds_base + lane*16 (wave-uniform base required)
static __device__ __forceinline__ void gload16(const u16* g, u16* l) {
    __builtin_amdgcn_global_load_lds((g1_void*)g, (l3_void*)l, 16, 0, 0);
}

// ---------------- weight convert: four 512x512 f32 -> bf16 ----------------
__global__ __launch_bounds__(256) void wconv_kernel(const float* __restrict__ w0,
                                                    const float* __restrict__ w1,
                                                    const float* __restrict__ w2,
                                                    const float* __restrict__ w3,
                                                    u16* __restrict__ wbf) {
    int i = blockIdx.x * 256 + threadIdx.x;      // 0..65535 float4 chunks
    int wsel = blockIdx.y;
    const float* src = (wsel == 0) ? w0 : (wsel == 1) ? w1 : (wsel == 2) ? w2 : w3;
    float4 v = reinterpret_cast<const float4*>(src)[i];
    ushort4 o;
    o.x = f2bf(v.x); o.y = f2bf(v.y); o.z = f2bf(v.z); o.w = f2bf(v.w);
    reinterpret_cast<ushort4*>(wbf + (size_t)wsel * CC * CC)[i] = o;
}

// ---------------- GroupNorm stats: one block per (group, batch) ----------------
__global__ __launch_bounds__(256) void gn_stats_kernel(const float* __restrict__ x,
                                                       float2* __restrict__ stats) {
    int g = blockIdx.x, b = blockIdx.y, t = threadIdx.x;
    const float4* xp = reinterpret_cast<const float4*>(x + ((size_t)b * CC + (size_t)g * CPG) * LL);
    float s = 0.f, ss = 0.f;
    for (int it = 0; it < 64; ++it) {
        float4 v = xp[it * 256 + t];
        s += v.x + v.y + v.z + v.w;
        ss += v.x * v.x + v.y * v.y + v.z * v.z + v.w * v.w;
    }
    #pragma unroll
    for (int off = 32; off; off >>= 1) { s += __shfl_xor(s, off, 64); ss += __shfl_xor(ss, off, 64); }
    __shared__ float rs[4], rss[4];
    int wave = t >> 6, lane = t & 63;
    if (lane == 0) { rs[wave] = s; rss[wave] = ss; }
    __syncthreads();
    if (t == 0) {
        float S = rs[0] + rs[1] + rs[2] + rs[3];
        float SS = rss[0] + rss[1] + rss[2] + rss[3];
        float mean = S * (1.f / 65536.f);
        float var = SS * (1.f / 65536.f) - mean * mean;
        var = fmaxf(var, 0.f);
        stats[b * NG + g] = make_float2(mean, rsqrtf(var + EPSV));
    }
}

// -------- GroupNorm normalize + transpose: x[b][c][l] f32 -> hT[b][l][c] bf16 --------
__global__ __launch_bounds__(256) void gn_norm_t_kernel(const float* __restrict__ x,
                                                        const float2* __restrict__ stats,
                                                        const float* __restrict__ gsc,
                                                        const float* __restrict__ gbi,
                                                        u16* __restrict__ hT) {
    int lt = blockIdx.x, ct = blockIdx.y, b = blockIdx.z;
    __shared__ u16 tile[64][72];
    int t = threadIdx.x;
    int cl0 = t >> 4, c4 = (t & 15) * 4;
    #pragma unroll
    for (int p = 0; p < 4; ++p) {
        int cl = p * 16 + cl0;
        int cg = ct * 64 + cl;
        float2 st = stats[b * NG + (cg >> 4)];
        float sc = gsc[cg] * st.y;
        float bi = gbi[cg];
        float4 v = *reinterpret_cast<const float4*>(x + ((size_t)b * CC + cg) * LL + lt * 64 + c4);
        tile[cl][c4 + 0] = f2bf((v.x - st.x) * sc + bi);
        tile[cl][c4 + 1] = f2bf((v.y - st.x) * sc + bi);
        tile[cl][c4 + 2] = f2bf((v.z - st.x) * sc + bi);
        tile[cl][c4 + 3] = f2bf((v.w - st.x) * sc + bi);
    }
    __syncthreads();
    int r = t >> 3, c8 = (t & 7) * 8;
    #pragma unroll
    for (int p = 0; p < 2; ++p) {
        int ll = p * 32 + r;
        s16x8 ov;
        #pragma unroll
        for (int j = 0; j < 8; ++j) ov[j] = (short)tile[c8 + j][ll];
        u16* hp = hT + ((size_t)b * LL + lt * 64 + ll) * CC + ct * 64 + c8;
        *reinterpret_cast<s16x8*>(hp) = ov;
    }
}

// ------------- plain bf16 transpose: src[b][4096][512] -> dst[b][512][4096] -------------
__global__ __launch_bounds__(256) void transpose_kernel(const u16* __restrict__ src,
                                                        u16* __restrict__ dst) {
    int rt = blockIdx.x, ct = blockIdx.y, b = blockIdx.z;
    __shared__ u16 tile[64][72];
    int t = threadIdx.x, r = t >> 3, c8 = (t & 7) * 8;
    #pragma unroll
    for (int p = 0; p < 2; ++p) {
        int rr = p * 32 + r;
        const u16* sp = src + ((size_t)b * LL + rt * 64 + rr) * CC + ct * 64 + c8;
        *reinterpret_cast<s16x8*>(&tile[rr][c8]) = *reinterpret_cast<const s16x8*>(sp);
    }
    __syncthreads();
    #pragma unroll
    for (int p = 0; p < 2; ++p) {
        int cc = p * 32 + r;
        s16x8 ov;
        #pragma unroll
        for (int j = 0; j < 8; ++j) ov[j] = (short)tile[c8 + j][cc];
        u16* dp = dst + ((size_t)b * CC + ct * 64 + cc) * LL + rt * 64 + c8;
        *reinterpret_cast<s16x8*>(dp) = ov;
    }
}

// --- final: out[b][co][l] = x[b][co][l] + pT[b][l][co]  (transpose + residual, f32 out) ---
__global__ __launch_bounds__(256) void final_kernel(const u16* __restrict__ pT,
                                                    const float* __restrict__ x,
                                                    float* __restrict__ out) {
    int lt = blockIdx.x, ct = blockIdx.y, b = blockIdx.z;
    __shared__ u16 tile[64][72];
    int t = threadIdx.x, r = t >> 3, c8 = (t & 7) * 8;
    #pragma unroll
    for (int p = 0; p < 2; ++p) {
        int rr = p * 32 + r;
        const u16* sp = pT + ((size_t)b * LL + lt * 64 + rr) * CC + ct * 64 + c8;
        *reinterpret_cast<s16x8*>(&tile[rr][c8]) = *reinterpret_cast<const s16x8*>(sp);
    }
    __syncthreads();
    #pragma unroll
    for (int p = 0; p < 2; ++p) {
        int cc = p * 32 + r;
        size_t off = ((size_t)b * CC + ct * 64 + cc) * LL + lt * 64 + c8;
        float4 x0 = *reinterpret_cast<const float4*>(x + off);
        float4 x1 = *reinterpret_cast<const float4*>(x + off + 4);
        float4 o0, o1;
        o0.x = x0.x + bf2f(tile[c8 + 0][cc]);
        o0.y = x0.y + bf2f(tile[c8 + 1][cc]);
        o0.z = x0.z + bf2f(tile[c8 + 2][cc]);
        o0.w = x0.w + bf2f(tile[c8 + 3][cc]);
        o1.x = x1.x + bf2f(tile[c8 + 4][cc]);
        o1.y = x1.y + bf2f(tile[c8 + 5][cc]);
        o1.z = x1.z + bf2f(tile[c8 + 6][cc]);
        o1.w = x1.w + bf2f(tile[c8 + 7][cc]);
        *reinterpret_cast<float4*>(out + off) = o0;
        *reinterpret_cast<float4*>(out + off + 4) = o1;
    }
}

// ---------------- generic GEMM: Out = A * B^T * scale + bias ----------------
// A: [b via asb][M][K] bf16, B: [b via bsb][N][K] bf16, Out: [b via osb][M][N] bf16.
// 128x128 tile, BK=32, global_load_lds w16, XOR-swizzled LDS (2-way alias = free),
// 4 waves 2x2, 16 MFMA/k-step/wave, coalesced LDS round-trip epilogue.
__global__ __launch_bounds__(256) void gemm_kernel(const u16* __restrict__ A, size_t asb,
                                                   const u16* __restrict__ B, size_t bsb,
                                                   const float* __restrict__ bias, float scale,
                                                   u16* __restrict__ Out, size_t osb,
                                                   int N, int K) {
    // pool: As = [0,4096) u16, Bs = [4096,8192); epilogue C tile = [0, 128*136)
    __shared__ u16 pool[128 * 136];
    u16* As = pool;
    u16* Bs = pool + 4096;
    int mt = blockIdx.x, nt = blockIdx.y, b = blockIdx.z;
    int t = threadIdx.x;
    int wave = t >> 6, lane = t & 63;
    int wm = (wave >> 1) * 64, wn = (wave & 1) * 64;
    int l15 = lane & 15, quad = lane >> 4;
    f32x4 acc[4][4] = {};
    const u16* Ab = A + (size_t)b * asb + (size_t)mt * 128 * K;
    const u16* Bb = B + (size_t)b * bsb + (size_t)nt * 128 * K;
    // Staging: LDS slot s (16B) holds global (row = s>>2, chunk = (s&3)^((s>>2)&3)^((s>>4)&3)).
    // Instr q of wave w covers slots q*256 + w*64 + lane; per-row chunks are a permutation,
    // so each 64B global row is still read contiguously (coalescing unchanged).
    int swzg = ((lane & 3) ^ ((lane >> 2) & 3) ^ ((lane >> 4) & 3)) * 8;
    int row0 = wave * 16 + (lane >> 2);
    int row1 = 64 + row0;
    const u16* Ap0 = Ab + (size_t)row0 * K + swzg;
    const u16* Ap1 = Ab + (size_t)row1 * K + swzg;
    const u16* Bp0 = Bb + (size_t)row0 * K + swzg;
    const u16* Bp1 = Bb + (size_t)row1 * K + swzg;
    u16* As0 = As + wave * 512;        u16* As1 = As + 2048 + wave * 512;
    u16* Bs0 = Bs + wave * 512;        u16* Bs1 = Bs + 2048 + wave * 512;
    // Fragment read: slot(R, chunk=quad) = R*4 + (quad ^ (R&3) ^ ((R>>2)&3));
    // with R = wbase + i*16 + l15 (wbase,i*16 mult of 16) the xor term is lane-constant.
    int swzf = (l15 & 3) ^ (l15 >> 2);
    int aoff = (wm + l15) * 32 + ((quad ^ swzf) * 8);
    int boff = (wn + l15) * 32 + ((quad ^ swzf) * 8);
    for (int k0 = 0; k0 < K; k0 += 32) {
        __syncthreads();
        gload16(Ap0 + k0, As0);
        gload16(Ap1 + k0, As1);
        gload16(Bp0 + k0, Bs0);
        gload16(Bp1 + k0, Bs1);
        __syncthreads();
        bf8v af[4], bfr[4];
        #pragma unroll
        for (int i = 0; i < 4; ++i)
            af[i] = ld_bf8(&As[aoff + i * 512]);
        #pragma unroll
        for (int j = 0; j < 4; ++j)
            bfr[j] = ld_bf8(&Bs[boff + j * 512]);
        #pragma unroll
        for (int i = 0; i < 4; ++i)
            #pragma unroll
            for (int j = 0; j < 4; ++j)
                acc[i][j] = __builtin_amdgcn_mfma_f32_16x16x32_bf16(af[i], bfr[j], acc[i][j], 0, 0, 0);
    }
    // ---- epilogue: acc -> bf16 LDS tile (stride 136) -> coalesced 16B stores ----
    __syncthreads();   // all fragment reads done before pool is overwritten
    #pragma unroll
    for (int j = 0; j < 4; ++j) {
        float bv = bias ? bias[nt * 128 + wn + j * 16 + l15] : 0.f;
        #pragma unroll
        for (int i = 0; i < 4; ++i) {
            #pragma unroll
            for (int r = 0; r < 4; ++r) {
                int row = wm + i * 16 + quad * 4 + r;
                int col = wn + j * 16 + l15;
                pool[row * 136 + col] = f2bf(acc[i][j][r] * scale + bv);
            }
        }
    }
    __syncthreads();
    u16* Ob = Out + (size_t)b * osb + (size_t)(mt * 128) * N + nt * 128;
    #pragma unroll
    for (int it = 0; it < 8; ++it) {
        int idx = it * 256 + t;
        int row = idx >> 4, ch = idx & 15;
        s16x8 val = *reinterpret_cast<const s16x8*>(&pool[row * 136 + ch * 8]);
        *reinterpret_cast<s16x8*>(Ob + (size_t)row * N + ch * 8) = val;
    }
}

// --------------- exact row softmax over S[b][i][0..4096), in place, bf16 ---------------
__global__ __launch_bounds__(256) void softmax_kernel(u16* __restrict__ S) {
    size_t row = (size_t)blockIdx.y * LL + blockIdx.x;
    u16* p = S + row * LL;
    int t = threadIdx.x;
    int wave = t >> 6, lane = t & 63;
    s16x8 v0 = reinterpret_cast<const s16x8*>(p)[t];
    s16x8 v1 = reinterpret_cast<const s16x8*>(p)[t + 256];
    float f[16];
    #pragma unroll
    for (int j = 0; j < 8; ++j) { f[j] = bf2f((u16)v0[j]); f[8 + j] = bf2f((u16)v1[j]); }
    float mx = f[0];
    #pragma unroll
    for (int j = 1; j < 16; ++j) mx = fmaxf(mx, f[j]);
    #pragma unroll
    for (int off = 32; off; off >>= 1) mx = fmaxf(mx, __shfl_xor(mx, off, 64));
    __shared__ float red[4];
    if (lane == 0) red[wave] = mx;
    __syncthreads();
    mx = fmaxf(fmaxf(red[0], red[1]), fmaxf(red[2], red[3]));
    float s = 0.f;
    #pragma unroll
    for (int j = 0; j < 16; ++j) { f[j] = __expf(f[j] - mx); s += f[j]; }
    #pragma unroll
    for (int off = 32; off; off >>= 1) s += __shfl_xor(s, off, 64);
    __syncthreads();
    if (lane == 0) red[wave] = s;
    __syncthreads();
    s = red[0] + red[1] + red[2] + red[3];
    float inv = 1.f / s;
    s16x8 o0, o1;
    #pragma unroll
    for (int j = 0; j < 8; ++j) { o0[j] = (short)f2bf(f[j] * inv); o1[j] = (short)f2bf(f[8 + j] * inv); }
    reinterpret_cast<s16x8*>(p)[t] = o0;
    reinterpret_cast<s16x8*>(p)[t + 256] = o1;
}

// ------------------------- flash attention (FALLBACK path only) -------------------------
__global__ __launch_bounds__(256) void attn_kernel(const u16* __restrict__ qT,
                                                   const u16* __restrict__ kT,
                                                   const u16* __restrict__ v,
                                                   u16* __restrict__ h2T) {
    const int D = CC;
    int b = blockIdx.y;
    int i0 = blockIdx.x * 32;
    int t = threadIdx.x;
    int wave = t >> 6, lane = t & 63;
    int l15 = lane & 15, quad = lane >> 4;
    int ih = wave >> 1, jh = wave & 1;
    int cb = jh * 256;

    __shared__ float SL[32 * 68];
    __shared__ u16 PL[32 * 72];
    __shared__ float mL[32], lL[32], aL[32];

    if (t < 32) { mL[t] = -1e30f; lL[t] = 0.f; }

    f32x4 opv[16] = {};
    const u16* qb = qT + ((size_t)b * LL + i0 + ih * 16 + l15) * D + quad * 8;
    const u16* kb = kT + (size_t)b * LL * D;
    const u16* vb = v + (size_t)b * D * LL;
    const float scale = 0.044194173824159216f;
    __syncthreads();

    for (int j0 = 0; j0 < LL; j0 += 64) {
        f32x4 sacc0 = {}, sacc1 = {};
        const u16* kp0 = kb + ((size_t)(j0 + jh * 32 + l15)) * D + quad * 8;
        const u16* kp1 = kp0 + (size_t)16 * D;
        #pragma unroll
        for (int kc = 0; kc < 16; ++kc) {
            bf8v a = ld_bf8(qb + kc * 32);
            bf8v b0 = ld_bf8(kp0 + kc * 32);
            bf8v b1 = ld_bf8(kp1 + kc * 32);
            sacc0 = __builtin_amdgcn_mfma_f32_16x16x32_bf16(a, b0, sacc0, 0, 0, 0);
            sacc1 = __builtin_amdgcn_mfma_f32_16x16x32_bf16(a, b1, sacc1, 0, 0, 0);
        }
        #pragma unroll
        for (int r = 0; r < 4; ++r) {
            SL[(ih * 16 + quad * 4 + r) * 68 + jh * 32 + l15] = sacc0[r] * scale;
            SL[(ih * 16 + quad * 4 + r) * 68 + jh * 32 + 16 + l15] = sacc1[r] * scale;
        }
        __syncthreads();
        {
            int row = t >> 3, c8 = (t & 7) * 8;
            float4 s0 = *reinterpret_cast<const float4*>(&SL[row * 68 + c8]);
            float4 s1 = *reinterpret_cast<const float4*>(&SL[row * 68 + c8 + 4]);
            float sv[8] = { s0.x, s0.y, s0.z, s0.w, s1.x, s1.y, s1.z, s1.w };
            float mx = sv[0];
            #pragma unroll
            for (int j = 1; j < 8; ++j) mx = fmaxf(mx, sv[j]);
            #pragma unroll
            for (int off = 1; off < 8; off <<= 1) mx = fmaxf(mx, __shfl_xor(mx, off, 64));
            float mold = mL[row];
            float mnew = fmaxf(mold, mx);
            float alpha = __expf(mold - mnew);
            float s = 0.f;
            #pragma unroll
            for (int j = 0; j < 8; ++j) { float pp = __expf(sv[j] - mnew); sv[j] = pp; s += pp; }
            #pragma unroll
            for (int off = 1; off < 8; off <<= 1) s += __shfl_xor(s, off, 64);
            ushort4 p0, p1;
            p0.x = f2bf(sv[0]); p0.y = f2bf(sv[1]); p0.z = f2bf(sv[2]); p0.w = f2bf(sv[3]);
            p1.x = f2bf(sv[4]); p1.y = f2bf(sv[5]); p1.z = f2bf(sv[6]); p1.w = f2bf(sv[7]);
            *reinterpret_cast<ushort4*>(&PL[row * 72 + c8]) = p0;
            *reinterpret_cast<ushort4*>(&PL[row * 72 + c8 + 4]) = p1;
            if ((t & 7) == 0) {
                lL[row] = lL[row] * alpha + s;
                mL[row] = mnew;
                aL[row] = alpha;
            }
        }
        __syncthreads();
        float al[4];
        #pragma unroll
        for (int r = 0; r < 4; ++r) al[r] = aL[ih * 16 + quad * 4 + r];
        #pragma unroll
        for (int nt2 = 0; nt2 < 16; ++nt2)
            #pragma unroll
            for (int r = 0; r < 4; ++r) opv[nt2][r] *= al[r];
        #pragma unroll
        for (int kk = 0; kk < 2; ++kk) {
            bf8v pa = ld_bf8(&PL[(ih * 16 + l15) * 72 + kk * 32 + quad * 8]);
            #pragma unroll
            for (int nt2 = 0; nt2 < 16; ++nt2) {
                const u16* vp = vb + (size_t)(cb + nt2 * 16 + l15) * LL + j0 + kk * 32 + quad * 8;
                bf8v bv = ld_bf8(vp);
                opv[nt2] = __builtin_amdgcn_mfma_f32_16x16x32_bf16(pa, bv, opv[nt2], 0, 0, 0);
            }
        }
        __syncthreads();
    }
    float il[4];
    #pragma unroll
    for (int r = 0; r < 4; ++r) il[r] = 1.f / lL[ih * 16 + quad * 4 + r];
    #pragma unroll
    for (int nt2 = 0; nt2 < 16; ++nt2) {
        #pragma unroll
        for (int r = 0; r < 4; ++r) {
            int irow = ih * 16 + quad * 4 + r;
            h2T[((size_t)b * LL + i0 + irow) * D + cb + nt2 * 16 + l15] = f2bf(opv[nt2][r] * il[r]);
        }
    }
}

extern "C" void kernel_launch(void* const* d_in, const int* in_sizes, int n_in,
                              void* d_out, int out_size, void* d_ws, size_t ws_size,
                              hipStream_t stream) {
    const float* x   = (const float*)d_in[0];
    const float* gsc = (const float*)d_in[1];
    const float* gbi = (const float*)d_in[2];
    const float* wq  = (const float*)d_in[3];
    const float* bq  = (const float*)d_in[4];
    const float* wk  = (const float*)d_in[5];
    const float* bk  = (const float*)d_in[6];
    const float* wv  = (const float*)d_in[7];
    const float* bv  = (const float*)d_in[8];
    const float* wp  = (const float*)d_in[9];
    const float* bp  = (const float*)d_in[10];
    float* out = (float*)d_out;

    char* ws = (char*)d_ws;
    const size_t SZ   = (size_t)BB * LL * CC * 2;     // 16 MiB per [b][l][c] bf16 buffer
    const size_t WQSZ = (size_t)4 * CC * CC * 2;      // 2 MiB bf16 weights
    const size_t SSZ  = (size_t)BB * LL * LL * 2;     // 128 MiB bf16 scores (all batches)
    u16* bufA = (u16*)(ws);                  // hT -> vv
    u16* bufB = (u16*)(ws + SZ);             // qT -> pT
    u16* bufC = (u16*)(ws + 2 * SZ);         // kT
    u16* bufD = (u16*)(ws + 3 * SZ);         // vT -> h2T
    u16* wbf  = (u16*)(ws + 4 * SZ);
    float2* stats = (float2*)(ws + 4 * SZ + WQSZ);
    u16* Sbuf = (u16*)(ws + 4 * SZ + WQSZ + 4096);
    const size_t NEEDED = 4 * SZ + WQSZ + 4096 + SSZ;
    const float scale = 0.044194173824159216f;        // 512^-0.5
    const size_t BLC = (size_t)LL * CC;

    wconv_kernel<<<dim3(256, 4), 256, 0, stream>>>(wq, wk, wv, wp, wbf);
    gn_stats_kernel<<<dim3(NG, BB), 256, 0, stream>>>(x, stats);
    gn_norm_t_kernel<<<dim3(64, 8, BB), 256, 0, stream>>>(x, stats, gsc, gbi, bufA);
    gemm_kernel<<<dim3(32, 4, BB), 256, 0, stream>>>(bufA, BLC, wbf + 0 * CC * CC, 0, bq, 1.f, bufB, BLC, CC, CC);
    gemm_kernel<<<dim3(32, 4, BB), 256, 0, stream>>>(bufA, BLC, wbf + 1 * CC * CC, 0, bk, 1.f, bufC, BLC, CC, CC);
    gemm_kernel<<<dim3(32, 4, BB), 256, 0, stream>>>(bufA, BLC, wbf + 2 * CC * CC, 0, bv, 1.f, bufD, BLC, CC, CC);
    transpose_kernel<<<dim3(64, 8, BB), 256, 0, stream>>>(bufD, bufA);   // vT -> vv

    if (ws_size >= NEEDED) {
        // Two-pass attention: S = QK^T*scale (GEMM) -> exact softmax -> O = P V (GEMM)
        gemm_kernel<<<dim3(32, 32, BB), 256, 0, stream>>>(bufB, BLC, bufC, BLC, nullptr, scale,
                                                          Sbuf, (size_t)LL * LL, LL, CC);
        softmax_kernel<<<dim3(LL, BB), 256, 0, stream>>>(Sbuf);
        gemm_kernel<<<dim3(32, 4, BB), 256, 0, stream>>>(Sbuf, (size_t)LL * LL, bufA, (size_t)CC * LL,
                                                         nullptr, 1.f, bufD, BLC, CC, LL);
    } else {
        // Fallback: flash attention (round-2 path)
        attn_kernel<<<dim3(LL / 32, BB), 256, 0, stream>>>(bufB, bufC, bufA, bufD);
    }
    gemm_kernel<<<dim3(32, 4, BB), 256, 0, stream>>>(bufD, BLC, wbf + 3 * CC * CC, 0, bp, 1.f, bufB, BLC, CC, CC);
    final_kernel<<<dim3(64, 8, BB), 256, 0, stream>>>(bufB, x, out);
}

// Round 5
// 386.816 us; speedup vs baseline: 4.1966x; 1.1445x over previous
//
#include <hip/hip_runtime.h>
#include <math.h>

// Shapes (fixed by the problem): b=4, c=512, l=4096, 32 groups.
// Inputs/outputs are float32; internal compute path is bf16 MFMA.
#define BB 4
#define CC 512
#define LL 4096
#define NG 32
#define CPG 16
#define EPSV 1e-6f

typedef short s16x8 __attribute__((ext_vector_type(8)));
typedef __bf16 bf8v __attribute__((ext_vector_type(8)));
typedef float f32x4 __attribute__((ext_vector_type(4)));
typedef unsigned short u16;

typedef const __attribute__((address_space(1))) void g1_void;
typedef __attribute__((address_space(3))) void l3_void;

// raw barrier / waitcnt (memory clobber = compiler reorder fence, no vmcnt drain)
#define ASM_SBAR() asm volatile("s_barrier" ::: "memory")
#define ASM_WAITV(N) asm volatile("s_waitcnt vmcnt(" #N ")" ::: "memory")

static __device__ __forceinline__ float bf2f(u16 h) {
    unsigned int u = ((unsigned int)h) << 16;
    union { unsigned int u; float f; } c; c.u = u; return c.f;
}
static __device__ __forceinline__ u16 f2bf(float f) {
    union { float f; unsigned int u; } c; c.f = f;
    unsigned int lsb = (c.u >> 16) & 1u;
    c.u += 0x7fffu + lsb;           // round-to-nearest-even
    return (u16)(c.u >> 16);
}
static __device__ __forceinline__ bf8v ld_bf8(const u16* p) {
    return *reinterpret_cast<const bf8v*>(p);
}
// async global->LDS; HW writes lds_base + lane*16 (wave-uniform base required)
static __device__ __forceinline__ void gload16(const u16* g, u16* l) {
    __builtin_amdgcn_global_load_lds((g1_void*)g, (l3_void*)l, 16, 0, 0);
}

// ---------------- zero rowsum buffer ----------------
__global__ __launch_bounds__(256) void zero_kernel(float* __restrict__ p, int n) {
    int i = blockIdx.x * 256 + threadIdx.x;
    if (i < n) p[i] = 0.f;
}

// ---------------- weight convert: four 512x512 f32 -> bf16 ----------------
__global__ __launch_bounds__(256) void wconv_kernel(const float* __restrict__ w0,
                                                    const float* __restrict__ w1,
                                                    const float* __restrict__ w2,
                                                    const float* __restrict__ w3,
                                                    u16* __restrict__ wbf) {
    int i = blockIdx.x * 256 + threadIdx.x;      // 0..65535 float4 chunks
    int wsel = blockIdx.y;
    const float* src = (wsel == 0) ? w0 : (wsel == 1) ? w1 : (wsel == 2) ? w2 : w3;
    float4 v = reinterpret_cast<const float4*>(src)[i];
    ushort4 o;
    o.x = f2bf(v.x); o.y = f2bf(v.y); o.z = f2bf(v.z); o.w = f2bf(v.w);
    reinterpret_cast<ushort4*>(wbf + (size_t)wsel * CC * CC)[i] = o;
}

// ---------------- GroupNorm stats: one block per (group, batch) ----------------
__global__ __launch_bounds__(256) void gn_stats_kernel(const float* __restrict__ x,
                                                       float2* __restrict__ stats) {
    int g = blockIdx.x, b = blockIdx.y, t = threadIdx.x;
    const float4* xp = reinterpret_cast<const float4*>(x + ((size_t)b * CC + (size_t)g * CPG) * LL);
    float s = 0.f, ss = 0.f;
    for (int it = 0; it < 64; ++it) {
        float4 v = xp[it * 256 + t];
        s += v.x + v.y + v.z + v.w;
        ss += v.x * v.x + v.y * v.y + v.z * v.z + v.w * v.w;
    }
    #pragma unroll
    for (int off = 32; off; off >>= 1) { s += __shfl_xor(s, off, 64); ss += __shfl_xor(ss, off, 64); }
    __shared__ float rs[4], rss[4];
    int wave = t >> 6, lane = t & 63;
    if (lane == 0) { rs[wave] = s; rss[wave] = ss; }
    __syncthreads();
    if (t == 0) {
        float S = rs[0] + rs[1] + rs[2] + rs[3];
        float SS = rss[0] + rss[1] + rss[2] + rss[3];
        float mean = S * (1.f / 65536.f);
        float var = SS * (1.f / 65536.f) - mean * mean;
        var = fmaxf(var, 0.f);
        stats[b * NG + g] = make_float2(mean, rsqrtf(var + EPSV));
    }
}

// -------- GroupNorm normalize + transpose: x[b][c][l] f32 -> hT[b][l][c] bf16 --------
__global__ __launch_bounds__(256) void gn_norm_t_kernel(const float* __restrict__ x,
                                                        const float2* __restrict__ stats,
                                                        const float* __restrict__ gsc,
                                                        const float* __restrict__ gbi,
                                                        u16* __restrict__ hT) {
    int lt = blockIdx.x, ct = blockIdx.y, b = blockIdx.z;
    __shared__ u16 tile[64][72];
    int t = threadIdx.x;
    int cl0 = t >> 4, c4 = (t & 15) * 4;
    #pragma unroll
    for (int p = 0; p < 4; ++p) {
        int cl = p * 16 + cl0;
        int cg = ct * 64 + cl;
        float2 st = stats[b * NG + (cg >> 4)];
        float sc = gsc[cg] * st.y;
        float bi = gbi[cg];
        float4 v = *reinterpret_cast<const float4*>(x + ((size_t)b * CC + cg) * LL + lt * 64 + c4);
        tile[cl][c4 + 0] = f2bf((v.x - st.x) * sc + bi);
        tile[cl][c4 + 1] = f2bf((v.y - st.x) * sc + bi);
        tile[cl][c4 + 2] = f2bf((v.z - st.x) * sc + bi);
        tile[cl][c4 + 3] = f2bf((v.w - st.x) * sc + bi);
    }
    __syncthreads();
    int r = t >> 3, c8 = (t & 7) * 8;
    #pragma unroll
    for (int p = 0; p < 2; ++p) {
        int ll = p * 32 + r;
        s16x8 ov;
        #pragma unroll
        for (int j = 0; j < 8; ++j) ov[j] = (short)tile[c8 + j][ll];
        u16* hp = hT + ((size_t)b * LL + lt * 64 + ll) * CC + ct * 64 + c8;
        *reinterpret_cast<s16x8*>(hp) = ov;
    }
}

// ------------- plain bf16 transpose: src[b][4096][512] -> dst[b][512][4096] -------------
__global__ __launch_bounds__(256) void transpose_kernel(const u16* __restrict__ src,
                                                        u16* __restrict__ dst) {
    int rt = blockIdx.x, ct = blockIdx.y, b = blockIdx.z;
    __shared__ u16 tile[64][72];
    int t = threadIdx.x, r = t >> 3, c8 = (t & 7) * 8;
    #pragma unroll
    for (int p = 0; p < 2; ++p) {
        int rr = p * 32 + r;
        const u16* sp = src + ((size_t)b * LL + rt * 64 + rr) * CC + ct * 64 + c8;
        *reinterpret_cast<s16x8*>(&tile[rr][c8]) = *reinterpret_cast<const s16x8*>(sp);
    }
    __syncthreads();
    #pragma unroll
    for (int p = 0; p < 2; ++p) {
        int cc = p * 32 + r;
        s16x8 ov;
        #pragma unroll
        for (int j = 0; j < 8; ++j) ov[j] = (short)tile[c8 + j][cc];
        u16* dp = dst + ((size_t)b * CC + ct * 64 + cc) * LL + rt * 64 + c8;
        *reinterpret_cast<s16x8*>(dp) = ov;
    }
}

// --- final: out[b][co][l] = x[b][co][l] + pT[b][l][co]  (transpose + residual, f32 out) ---
__global__ __launch_bounds__(256) void final_kernel(const u16* __restrict__ pT,
                                                    const float* __restrict__ x,
                                                    float* __restrict__ out) {
    int lt = blockIdx.x, ct = blockIdx.y, b = blockIdx.z;
    __shared__ u16 tile[64][72];
    int t = threadIdx.x, r = t >> 3, c8 = (t & 7) * 8;
    #pragma unroll
    for (int p = 0; p < 2; ++p) {
        int rr = p * 32 + r;
        const u16* sp = pT + ((size_t)b * LL + lt * 64 + rr) * CC + ct * 64 + c8;
        *reinterpret_cast<s16x8*>(&tile[rr][c8]) = *reinterpret_cast<const s16x8*>(sp);
    }
    __syncthreads();
    #pragma unroll
    for (int p = 0; p < 2; ++p) {
        int cc = p * 32 + r;
        size_t off = ((size_t)b * CC + ct * 64 + cc) * LL + lt * 64 + c8;
        float4 x0 = *reinterpret_cast<const float4*>(x + off);
        float4 x1 = *reinterpret_cast<const float4*>(x + off + 4);
        float4 o0, o1;
        o0.x = x0.x + bf2f(tile[c8 + 0][cc]);
        o0.y = x0.y + bf2f(tile[c8 + 1][cc]);
        o0.z = x0.z + bf2f(tile[c8 + 2][cc]);
        o0.w = x0.w + bf2f(tile[c8 + 3][cc]);
        o1.x = x1.x + bf2f(tile[c8 + 4][cc]);
        o1.y = x1.y + bf2f(tile[c8 + 5][cc]);
        o1.z = x1.z + bf2f(tile[c8 + 6][cc]);
        o1.w = x1.w + bf2f(tile[c8 + 7][cc]);
        *reinterpret_cast<float4*>(out + off) = o0;
        *reinterpret_cast<float4*>(out + off + 4) = o1;
    }
}

// ---------------- generic GEMM: Out = f(A * B^T * scale) + bias ----------------
// mode 0: plain (+bias). mode 1: exp epilogue + atomic rowsum (attention S pass).
// mode 2: multiply rows by 1/rowsum (attention PV pass).
// Pipelined K-loop: 3 LDS buffers, prefetch distance 2, raw s_barrier + vmcnt(8/4/0)
// so prefetch loads stay in flight across barriers (no vmcnt(0) drain mid-loop).
__global__ __launch_bounds__(256) void gemm_kernel(const u16* __restrict__ A, size_t asb,
                                                   const u16* __restrict__ B, size_t bsb,
                                                   const float* __restrict__ bias, float scale,
                                                   u16* __restrict__ Out, size_t osb,
                                                   int N, int K, int mode,
                                                   float* __restrict__ rsum) {
    // pool: 3 x (As 8KB + Bs 8KB) = 48 KB; epilogue reuses [0, 128*136*2) = 34.8 KB
    __shared__ u16 pool[24576];
    u16* Asb = pool;             // 3 bufs of 4096 u16
    u16* Bsb = pool + 12288;     // 3 bufs of 4096 u16
    int mt = blockIdx.x, nt = blockIdx.y, b = blockIdx.z;
    int t = threadIdx.x;
    int wave = t >> 6, lane = t & 63;
    int wm = (wave >> 1) * 64, wn = (wave & 1) * 64;
    int l15 = lane & 15, quad = lane >> 4;
    f32x4 acc[4][4] = {};
    const u16* Ab = A + (size_t)b * asb + (size_t)mt * 128 * K;
    const u16* Bb = B + (size_t)b * bsb + (size_t)nt * 128 * K;
    // Staging: LDS slot s (16B) holds global (row = s>>2, chunk = (s&3)^((s>>2)&3)^((s>>4)&3)).
    int swzg = ((lane & 3) ^ ((lane >> 2) & 3) ^ ((lane >> 4) & 3)) * 8;
    int row0 = wave * 16 + (lane >> 2);
    int row1 = 64 + row0;
    const u16* Ap0 = Ab + (size_t)row0 * K + swzg;
    const u16* Ap1 = Ab + (size_t)row1 * K + swzg;
    const u16* Bp0 = Bb + (size_t)row0 * K + swzg;
    const u16* Bp1 = Bb + (size_t)row1 * K + swzg;
    int wo = wave * 512;
    // Fragment read swizzle (see round-4 derivation)
    int swzf = (l15 & 3) ^ (l15 >> 2);
    int aoff = (wm + l15) * 32 + ((quad ^ swzf) * 8);
    int boff = (wn + l15) * 32 + ((quad ^ swzf) * 8);
    const int iters = K >> 5;
    // prologue: chunk 0 -> buf0, chunk 1 -> buf1 (8 loads in flight)
    gload16(Ap0, Asb + wo);                 gload16(Ap1, Asb + 2048 + wo);
    gload16(Bp0, Bsb + wo);                 gload16(Bp1, Bsb + 2048 + wo);
    gload16(Ap0 + 32, Asb + 4096 + wo);     gload16(Ap1 + 32, Asb + 4096 + 2048 + wo);
    gload16(Bp0 + 32, Bsb + 4096 + wo);     gload16(Bp1 + 32, Bsb + 4096 + 2048 + wo);
    int cur = 0;
    for (int i = 0; i < iters; ++i) {
        if (i + 2 < iters) {
            int pf = cur + 2; if (pf >= 3) pf -= 3;
            int kk = (i + 2) * 32;
            u16* as = Asb + pf * 4096; u16* bs = Bsb + pf * 4096;
            gload16(Ap0 + kk, as + wo);        gload16(Ap1 + kk, as + 2048 + wo);
            gload16(Bp0 + kk, bs + wo);        gload16(Bp1 + kk, bs + 2048 + wo);
            ASM_WAITV(8);      // chunk i's 4 loads retired; 8 newer stay in flight
        } else if (i + 1 < iters) {
            ASM_WAITV(4);
        } else {
            ASM_WAITV(0);
        }
        ASM_SBAR();            // all waves' chunk-i loads landed
        const u16* As = Asb + cur * 4096;
        const u16* Bs = Bsb + cur * 4096;
        bf8v af[4], bfr[4];
        #pragma unroll
        for (int ii = 0; ii < 4; ++ii)
            af[ii] = ld_bf8(&As[aoff + ii * 512]);
        #pragma unroll
        for (int j = 0; j < 4; ++j)
            bfr[j] = ld_bf8(&Bs[boff + j * 512]);
        #pragma unroll
        for (int ii = 0; ii < 4; ++ii)
            #pragma unroll
            for (int j = 0; j < 4; ++j)
                acc[ii][j] = __builtin_amdgcn_mfma_f32_16x16x32_bf16(af[ii], bfr[j], acc[ii][j], 0, 0, 0);
        ASM_SBAR();            // reads of buf cur done before it is refilled (iter i+1)
        cur = (cur == 2) ? 0 : cur + 1;
    }
    // ---- epilogue: acc -> bf16 LDS tile (stride 136) -> coalesced 16B stores ----
    __syncthreads();
    if (mode == 1) {
        // P' = exp(S*scale), no max subtraction (|S| << 88, f32-exp safe)
        #pragma unroll
        for (int j = 0; j < 4; ++j)
            #pragma unroll
            for (int i = 0; i < 4; ++i)
                #pragma unroll
                for (int r = 0; r < 4; ++r) {
                    int row = wm + i * 16 + quad * 4 + r;
                    int col = wn + j * 16 + l15;
                    pool[row * 136 + col] = f2bf(__expf(acc[i][j][r] * scale));
                }
    } else {
        float invl[4][4];
        if (mode == 2) {
            #pragma unroll
            for (int i = 0; i < 4; ++i)
                #pragma unroll
                for (int r = 0; r < 4; ++r)
                    invl[i][r] = 1.f / rsum[(size_t)b * LL + mt * 128 + wm + i * 16 + quad * 4 + r];
        }
        #pragma unroll
        for (int j = 0; j < 4; ++j) {
            float bv = bias ? bias[nt * 128 + wn + j * 16 + l15] : 0.f;
            #pragma unroll
            for (int i = 0; i < 4; ++i)
                #pragma unroll
                for (int r = 0; r < 4; ++r) {
                    int row = wm + i * 16 + quad * 4 + r;
                    int col = wn + j * 16 + l15;
                    float val = acc[i][j][r] * scale;
                    if (mode == 2) val *= invl[i][r];
                    pool[row * 136 + col] = f2bf(val + bv);
                }
        }
    }
    __syncthreads();
    u16* Ob = Out + (size_t)b * osb + (size_t)(mt * 128) * N + nt * 128;
    #pragma unroll
    for (int it = 0; it < 8; ++it) {
        int idx = it * 256 + t;
        int row = idx >> 4, ch = idx & 15;
        s16x8 val = *reinterpret_cast<const s16x8*>(&pool[row * 136 + ch * 8]);
        *reinterpret_cast<s16x8*>(Ob + (size_t)row * N + ch * 8) = val;
        if (mode == 1) {
            float part = 0.f;
            #pragma unroll
            for (int j = 0; j < 8; ++j) part += bf2f((u16)val[j]);
            part += __shfl_xor(part, 1, 64);
            part += __shfl_xor(part, 2, 64);
            part += __shfl_xor(part, 4, 64);
            part += __shfl_xor(part, 8, 64);
            if ((t & 15) == 0)
                atomicAdd(rsum + (size_t)b * LL + mt * 128 + row, part);
        }
    }
}

// ------------------------- flash attention (FALLBACK path only) -------------------------
__global__ __launch_bounds__(256) void attn_kernel(const u16* __restrict__ qT,
                                                   const u16* __restrict__ kT,
                                                   const u16* __restrict__ v,
                                                   u16* __restrict__ h2T) {
    const int D = CC;
    int b = blockIdx.y;
    int i0 = blockIdx.x * 32;
    int t = threadIdx.x;
    int wave = t >> 6, lane = t & 63;
    int l15 = lane & 15, quad = lane >> 4;
    int ih = wave >> 1, jh = wave & 1;
    int cb = jh * 256;

    __shared__ float SL[32 * 68];
    __shared__ u16 PL[32 * 72];
    __shared__ float mL[32], lL[32], aL[32];

    if (t < 32) { mL[t] = -1e30f; lL[t] = 0.f; }

    f32x4 opv[16] = {};
    const u16* qb = qT + ((size_t)b * LL + i0 + ih * 16 + l15) * D + quad * 8;
    const u16* kb = kT + (size_t)b * LL * D;
    const u16* vb = v + (size_t)b * D * LL;
    const float scale = 0.044194173824159216f;
    __syncthreads();

    for (int j0 = 0; j0 < LL; j0 += 64) {
        f32x4 sacc0 = {}, sacc1 = {};
        const u16* kp0 = kb + ((size_t)(j0 + jh * 32 + l15)) * D + quad * 8;
        const u16* kp1 = kp0 + (size_t)16 * D;
        #pragma unroll
        for (int kc = 0; kc < 16; ++kc) {
            bf8v a = ld_bf8(qb + kc * 32);
            bf8v b0 = ld_bf8(kp0 + kc * 32);
            bf8v b1 = ld_bf8(kp1 + kc * 32);
            sacc0 = __builtin_amdgcn_mfma_f32_16x16x32_bf16(a, b0, sacc0, 0, 0, 0);
            sacc1 = __builtin_amdgcn_mfma_f32_16x16x32_bf16(a, b1, sacc1, 0, 0, 0);
        }
        #pragma unroll
        for (int r = 0; r < 4; ++r) {
            SL[(ih * 16 + quad * 4 + r) * 68 + jh * 32 + l15] = sacc0[r] * scale;
            SL[(ih * 16 + quad * 4 + r) * 68 + jh * 32 + 16 + l15] = sacc1[r] * scale;
        }
        __syncthreads();
        {
            int row = t >> 3, c8 = (t & 7) * 8;
            float4 s0 = *reinterpret_cast<const float4*>(&SL[row * 68 + c8]);
            float4 s1 = *reinterpret_cast<const float4*>(&SL[row * 68 + c8 + 4]);
            float sv[8] = { s0.x, s0.y, s0.z, s0.w, s1.x, s1.y, s1.z, s1.w };
            float mx = sv[0];
            #pragma unroll
            for (int j = 1; j < 8; ++j) mx = fmaxf(mx, sv[j]);
            #pragma unroll
            for (int off = 1; off < 8; off <<= 1) mx = fmaxf(mx, __shfl_xor(mx, off, 64));
            float mold = mL[row];
            float mnew = fmaxf(mold, mx);
            float alpha = __expf(mold - mnew);
            float s = 0.f;
            #pragma unroll
            for (int j = 0; j < 8; ++j) { float pp = __expf(sv[j] - mnew); sv[j] = pp; s += pp; }
            #pragma unroll
            for (int off = 1; off < 8; off <<= 1) s += __shfl_xor(s, off, 64);
            ushort4 p0, p1;
            p0.x = f2bf(sv[0]); p0.y = f2bf(sv[1]); p0.z = f2bf(sv[2]); p0.w = f2bf(sv[3]);
            p1.x = f2bf(sv[4]); p1.y = f2bf(sv[5]); p1.z = f2bf(sv[6]); p1.w = f2bf(sv[7]);
            *reinterpret_cast<ushort4*>(&PL[row * 72 + c8]) = p0;
            *reinterpret_cast<ushort4*>(&PL[row * 72 + c8 + 4]) = p1;
            if ((t & 7) == 0) {
                lL[row] = lL[row] * alpha + s;
                mL[row] = mnew;
                aL[row] = alpha;
            }
        }
        __syncthreads();
        float al[4];
        #pragma unroll
        for (int r = 0; r < 4; ++r) al[r] = aL[ih * 16 + quad * 4 + r];
        #pragma unroll
        for (int nt2 = 0; nt2 < 16; ++nt2)
            #pragma unroll
            for (int r = 0; r < 4; ++r) opv[nt2][r] *= al[r];
        #pragma unroll
        for (int kk = 0; kk < 2; ++kk) {
            bf8v pa = ld_bf8(&PL[(ih * 16 + l15) * 72 + kk * 32 + quad * 8]);
            #pragma unroll
            for (int nt2 = 0; nt2 < 16; ++nt2) {
                const u16* vp = vb + (size_t)(cb + nt2 * 16 + l15) * LL + j0 + kk * 32 + quad * 8;
                bf8v bv = ld_bf8(vp);
                opv[nt2] = __builtin_amdgcn_mfma_f32_16x16x32_bf16(pa, bv, opv[nt2], 0, 0, 0);
            }
        }
        __syncthreads();
    }
    float il[4];
    #pragma unroll
    for (int r = 0; r < 4; ++r) il[r] = 1.f / lL[ih * 16 + quad * 4 + r];
    #pragma unroll
    for (int nt2 = 0; nt2 < 16; ++nt2) {
        #pragma unroll
        for (int r = 0; r < 4; ++r) {
            int irow = ih * 16 + quad * 4 + r;
            h2T[((size_t)b * LL + i0 + irow) * D + cb + nt2 * 16 + l15] = f2bf(opv[nt2][r] * il[r]);
        }
    }
}

extern "C" void kernel_launch(void* const* d_in, const int* in_sizes, int n_in,
                              void* d_out, int out_size, void* d_ws, size_t ws_size,
                              hipStream_t stream) {
    const float* x   = (const float*)d_in[0];
    const float* gsc = (const float*)d_in[1];
    const float* gbi = (const float*)d_in[2];
    const float* wq  = (const float*)d_in[3];
    const float* bq  = (const float*)d_in[4];
    const float* wk  = (const float*)d_in[5];
    const float* bk  = (const float*)d_in[6];
    const float* wv  = (const float*)d_in[7];
    const float* bv  = (const float*)d_in[8];
    const float* wp  = (const float*)d_in[9];
    const float* bp  = (const float*)d_in[10];
    float* out = (float*)d_out;

    char* ws = (char*)d_ws;
    const size_t SZ   = (size_t)BB * LL * CC * 2;     // 16 MiB per [b][l][c] bf16 buffer
    const size_t WQSZ = (size_t)4 * CC * CC * 2;      // 2 MiB bf16 weights
    const size_t SSZ  = (size_t)BB * LL * LL * 2;     // 128 MiB bf16 scores (all batches)
    const size_t RSZ  = (size_t)BB * LL * 4;          // 64 KiB f32 rowsums
    u16* bufA = (u16*)(ws);                  // hT -> vv
    u16* bufB = (u16*)(ws + SZ);             // qT -> pT
    u16* bufC = (u16*)(ws + 2 * SZ);         // kT
    u16* bufD = (u16*)(ws + 3 * SZ);         // vT -> h2T
    u16* wbf  = (u16*)(ws + 4 * SZ);
    float2* stats = (float2*)(ws + 4 * SZ + WQSZ);
    float* rowsum = (float*)(ws + 4 * SZ + WQSZ + 4096);
    u16* Sbuf = (u16*)(ws + 4 * SZ + WQSZ + 4096 + RSZ);
    const size_t NEEDED = 4 * SZ + WQSZ + 4096 + RSZ + SSZ;
    const float scale = 0.044194173824159216f;        // 512^-0.5
    const size_t BLC = (size_t)LL * CC;

    wconv_kernel<<<dim3(256, 4), 256, 0, stream>>>(wq, wk, wv, wp, wbf);
    gn_stats_kernel<<<dim3(NG, BB), 256, 0, stream>>>(x, stats);
    gn_norm_t_kernel<<<dim3(64, 8, BB), 256, 0, stream>>>(x, stats, gsc, gbi, bufA);
    gemm_kernel<<<dim3(32, 4, BB), 256, 0, stream>>>(bufA, BLC, wbf + 0 * CC * CC, 0, bq, 1.f, bufB, BLC, CC, CC, 0, nullptr);
    gemm_kernel<<<dim3(32, 4, BB), 256, 0, stream>>>(bufA, BLC, wbf + 1 * CC * CC, 0, bk, 1.f, bufC, BLC, CC, CC, 0, nullptr);
    gemm_kernel<<<dim3(32, 4, BB), 256, 0, stream>>>(bufA, BLC, wbf + 2 * CC * CC, 0, bv, 1.f, bufD, BLC, CC, CC, 0, nullptr);
    transpose_kernel<<<dim3(64, 8, BB), 256, 0, stream>>>(bufD, bufA);   // vT -> vv

    if (ws_size >= NEEDED) {
        // Two-pass attention, softmax fused into GEMM epilogues:
        //   P' = exp(QK^T*scale) with atomic rowsums; O = (P' V) / rowsum
        zero_kernel<<<dim3((BB * LL + 255) / 256), 256, 0, stream>>>(rowsum, BB * LL);
        gemm_kernel<<<dim3(32, 32, BB), 256, 0, stream>>>(bufB, BLC, bufC, BLC, nullptr, scale,
                                                          Sbuf, (size_t)LL * LL, LL, CC, 1, rowsum);
        gemm_kernel<<<dim3(32, 4, BB), 256, 0, stream>>>(Sbuf, (size_t)LL * LL, bufA, (size_t)CC * LL,
                                                         nullptr, 1.f, bufD, BLC, CC, LL, 2, rowsum);
    } else {
        // Fallback: flash attention (round-2 path)
        attn_kernel<<<dim3(LL / 32, BB), 256, 0, stream>>>(bufB, bufC, bufA, bufD);
    }
    gemm_kernel<<<dim3(32, 4, BB), 256, 0, stream>>>(bufD, BLC, wbf + 3 * CC * CC, 0, bp, 1.f, bufB, BLC, CC, CC, 0, nullptr);
    final_kernel<<<dim3(64, 8, BB), 256, 0, stream>>>(bufB, x, out);
}